// Round 10
// baseline (107.268 us; speedup 1.0000x reference)
//
#include <hip/hip_runtime.h>

// Problem constants (fixed by reference setup_inputs)
#define HW 262144    // 512*512 pixels per image
#define NB 8         // batch
#define NC 32        // channels
#define NK 8         // num classes (NUM_IDS)

typedef float f4 __attribute__((ext_vector_type(4)));

// ws layout (floats) — every slot fully overwritten each launch, no init,
// no atomics anywhere.
//   psum  [4096][8]  @ 0      per-(b,c,chunk) class channel sums
//   pcnt  [128][8]   @ 32768  per-(b,chunk) class counts
//   meansT[8][32][8] @ 33792  transposed [b][c][k]
//   counts[8][8]     @ 35840
//   pdist [2048][8]  @ 35904  per-(b,chunk) class dist sums
#define WS_PSUM 0
#define WS_PCNT 32768
#define WS_MT   33792
#define WS_CNT  35840
#define WS_PD   35904

// ---------------------------------------------------------------------------
// Pass 1: per-class channel partial sums. One block = (b, c, 16K-px chunk).
// Per-thread LDS slots (stride 9: coprime with 32 banks -> <=2-way, free).
// No atomics. b = f&7: XCD (heuristic f%8) owns one image.
// SINGLE CHANGE vs R4: emb loads are PLAIN (no nontemporal hint) so the
// Infinity Cache retains pass-1 lines for pass 2's re-read (R6 profile:
// k_dist FETCH was already only 135/264 MB *with* the evict-first hint).
// c==0 blocks also compute label counts (labels L2-hot on re-read).
// ---------------------------------------------------------------------------
__global__ __launch_bounds__(256) void k_pass1(const float* __restrict__ emb,
                                               const int* __restrict__ lab,
                                               float* __restrict__ psum,
                                               float* __restrict__ pcnt) {
    __shared__ float slots[256 * 9];
    __shared__ float red[256];
    const int t = threadIdx.x;
    const int f = blockIdx.x;
    const int b = f & 7;
    const int o = f >> 3;        // 0..511 per image
    const int chunk = o >> 5;    // 0..15
    const int c = o & 31;

    float* myslot = &slots[t * 9];
#pragma unroll
    for (int i = 0; i < 9; ++i) myslot[i] = 0.f;

    const float* e = emb + ((size_t)(b * NC + c)) * HW;
    const int* lb = lab + (size_t)b * HW;
    const int base = chunk * 16384;

    for (int it = 0; it < 16; ++it) {
        const int p = base + it * 1024 + t * 4;
        const int4 l4 = *reinterpret_cast<const int4*>(lb + p);
        const f4 e4 = *reinterpret_cast<const f4*>(e + p);   // plain load: keep in L3
        myslot[l4.x] += e4.x;
        myslot[l4.y] += e4.y;
        myslot[l4.z] += e4.z;
        myslot[l4.w] += e4.w;
    }
    __syncthreads();

    {   // reduce slots[256][8] -> 8
        const int k = t & 7, r = t >> 3;
        float s = 0.f;
#pragma unroll
        for (int i = 0; i < 8; ++i) s += slots[(r + 32 * i) * 9 + k];
        red[r * 8 + k] = s;
    }
    __syncthreads();
    if (t < 8) {
        float s = 0.f;
#pragma unroll
        for (int r = 0; r < 32; ++r) s += red[r * 8 + t];
        psum[(size_t)f * 8 + t] = s;   // f encodes (b,c,chunk)
    }

    // counts: only c==0 blocks; labels re-read from L2
    if (c == 0) {
        __syncthreads();
#pragma unroll
        for (int i = 0; i < 9; ++i) myslot[i] = 0.f;
        for (int it = 0; it < 16; ++it) {
            const int p = base + it * 1024 + t * 4;
            const int4 l4 = *reinterpret_cast<const int4*>(lb + p);
            myslot[l4.x] += 1.f;
            myslot[l4.y] += 1.f;
            myslot[l4.z] += 1.f;
            myslot[l4.w] += 1.f;
        }
        __syncthreads();
        {
            const int k = t & 7, r = t >> 3;
            float s = 0.f;
#pragma unroll
            for (int i = 0; i < 8; ++i) s += slots[(r + 32 * i) * 9 + k];
            red[r * 8 + k] = s;
        }
        __syncthreads();
        if (t < 8) {
            float s = 0.f;
#pragma unroll
            for (int r = 0; r < 32; ++r) s += red[r * 8 + t];
            pcnt[(b * 16 + chunk) * 8 + t] = s;
        }
    }
}

// ---------------------------------------------------------------------------
// Reduce partials -> meansT [b][c][k] + counts [b][k]. 8 blocks (R4-verbatim).
// ---------------------------------------------------------------------------
__global__ __launch_bounds__(256) void k_means(const float* __restrict__ psum,
                                               const float* __restrict__ pcnt,
                                               float* __restrict__ mt,
                                               float* __restrict__ cnt) {
    const int b = blockIdx.x;
    const int t = threadIdx.x;
    const int c = t >> 3, k = t & 7;

    float cn = 0.f;
#pragma unroll
    for (int ch = 0; ch < 16; ++ch) cn += pcnt[(b * 16 + ch) * 8 + k];

    float s = 0.f;
#pragma unroll
    for (int ch = 0; ch < 16; ++ch) s += psum[(size_t)(b + 8 * (c + 32 * ch)) * 8 + k];

    mt[b * 256 + c * 8 + k] = s / cn;
    if (c == 0) cnt[b * 8 + k] = cn;
}

// ---------------------------------------------------------------------------
// Pass 2 (R4-verbatim): per-pixel distance to class mean, segment-summed.
// One block = (b, 1024-px chunk); 4 px/thread; means in LDS transposed
// [c][k]. emb loads KEEP the nontemporal hint: pass-2 miss-fills are
// evict-first so they don't displace the L3-resident not-yet-read lines.
// Block writes its own pd slot — no atomics.
// ---------------------------------------------------------------------------
__global__ __launch_bounds__(256) void k_dist(const float* __restrict__ emb,
                                              const int* __restrict__ lab,
                                              const float* __restrict__ mt,
                                              float* __restrict__ pd) {
    __shared__ float mT[256];
    __shared__ float slots[256 * 9];
    __shared__ float red[256];
    const int t = threadIdx.x;
    const int f = blockIdx.x;
    const int b = f & 7;
    const int chunk = f >> 3;  // 0..255

    mT[t] = mt[b * 256 + t];
    float* myslot = &slots[t * 9];
#pragma unroll
    for (int i = 0; i < 9; ++i) myslot[i] = 0.f;
    __syncthreads();

    const int p = chunk * 1024 + t * 4;
    const int4 l4 = *reinterpret_cast<const int4*>(lab + (size_t)b * HW + p);
    const float* e = emb + (size_t)b * NC * HW + p;

    float a0 = 0.f, a1 = 0.f, a2 = 0.f, a3 = 0.f;
#pragma unroll 8
    for (int c = 0; c < NC; ++c) {
        const f4 e4 = __builtin_nontemporal_load(reinterpret_cast<const f4*>(e + (size_t)c * HW));
        const float* mrow = &mT[c * 8];
        const float d0 = e4.x - mrow[l4.x];
        const float d1 = e4.y - mrow[l4.y];
        const float d2 = e4.z - mrow[l4.z];
        const float d3 = e4.w - mrow[l4.w];
        a0 += d0 * d0;
        a1 += d1 * d1;
        a2 += d2 * d2;
        a3 += d3 * d3;
    }
    myslot[l4.x] += sqrtf(a0);
    myslot[l4.y] += sqrtf(a1);
    myslot[l4.z] += sqrtf(a2);
    myslot[l4.w] += sqrtf(a3);
    __syncthreads();

    {
        const int k = t & 7, r = t >> 3;
        float s = 0.f;
#pragma unroll
        for (int i = 0; i < 8; ++i) s += slots[(r + 32 * i) * 9 + k];
        red[r * 8 + k] = s;
    }
    __syncthreads();
    if (t < 8) {
        float s = 0.f;
#pragma unroll
        for (int r = 0; r < 32; ++r) s += red[r * 8 + t];
        pd[(size_t)f * 8 + t] = s;
    }
}

// ---------------------------------------------------------------------------
// Epilogue (R4-verbatim): coalesced pd reduce (thread t sums flat idx t,
// t+256, ...; residue mod 64 = b*8+k), var + hinge. Deterministic.
// ---------------------------------------------------------------------------
__global__ __launch_bounds__(256) void k_final(const float* __restrict__ pd,
                                               const float* __restrict__ cnt,
                                               const float* __restrict__ mt,
                                               float* __restrict__ out) {
    __shared__ float partial[256];
    __shared__ float distsum[64];   // [b][k]
    __shared__ float varl[8];
    __shared__ float hingeL[8 * 21];
    const int t = threadIdx.x;

    {
        float s = 0.f;
        for (int j = 0; j < 64; ++j) s += pd[(size_t)j * 256 + t];
        partial[t] = s;
    }
    __syncthreads();
    if (t < 64)
        distsum[t] = partial[t] + partial[t + 64] + partial[t + 128] + partial[t + 192];
    __syncthreads();

    if (t < 8) {
        float v = 0.f;
#pragma unroll
        for (int k = 1; k < 8; ++k)
            v += distsum[t * 8 + k] / cnt[t * 8 + k];
        varl[t] = v;
    }

    if (t < 168) {  // 8 images * 21 pairs among clusters 1..7
        const int b = t / 21;
        const int pr = t - b * 21;
        int ii = 1, jj = 2, c2 = 0;
        for (int a = 1; a <= 7; ++a)
            for (int bb = a + 1; bb <= 7; ++bb) {
                if (c2 == pr) { ii = a; jj = bb; }
                ++c2;
            }
        const float* mTb = mt + b * 256;
        float sq = 0.f;
#pragma unroll
        for (int c = 0; c < NC; ++c) {
            const float d = mTb[c * 8 + ii] - mTb[c * 8 + jj];
            sq += d * d;
        }
        const float dist = sqrtf(sq);
        const float gap = 5.0f - dist;  // 2*DD = 5.0
        hingeL[t] = (dist < 5.0f) ? gap * gap : 0.f;
    }
    __syncthreads();
    if (t == 0) {
        float s = 0.f;
#pragma unroll
        for (int b = 0; b < 8; ++b) {
            float h = 0.f;
            for (int pr = 0; pr < 21; ++pr) h += hingeL[b * 21 + pr];
            s += (varl[b] + h * (1.0f / 6.0f)) * (1.0f / 7.0f);
        }
        out[0] = s * 0.125f;
    }
}

extern "C" void kernel_launch(void* const* d_in, const int* in_sizes, int n_in,
                              void* d_out, int out_size, void* d_ws, size_t ws_size,
                              hipStream_t stream) {
    const float* emb = (const float*)d_in[0];
    const int* lab = (const int*)d_in[1];
    float* out = (float*)d_out;
    float* ws = (float*)d_ws;

    float* psum = ws + WS_PSUM;
    float* pcnt = ws + WS_PCNT;
    float* mt = ws + WS_MT;
    float* cnt = ws + WS_CNT;
    float* pd = ws + WS_PD;

    k_pass1<<<NB * 16 * NC, 256, 0, stream>>>(emb, lab, psum, pcnt);
    k_means<<<NB, 256, 0, stream>>>(psum, pcnt, mt, cnt);
    k_dist<<<NB * 256, 256, 0, stream>>>(emb, lab, mt, pd);
    k_final<<<1, 256, 0, stream>>>(pd, cnt, mt, out);
}

// Round 11
// 104.303 us; speedup vs baseline: 1.0284x; 1.0284x over previous
//
#include <hip/hip_runtime.h>

// Problem constants (fixed by reference setup_inputs)
#define HW 262144    // 512*512 pixels per image
#define NB 8         // batch
#define NC 32        // channels
#define NK 8         // num classes (NUM_IDS)

typedef float f4 __attribute__((ext_vector_type(4)));

// ws layout (floats) — every slot fully overwritten each launch, no init,
// no atomics anywhere. Total ~210 KB.
//   psum [4096][8]  @ 0      per-(b,c,chunk) class channel sums
//   pcnt [128][8]   @ 32768  per-(b,chunk) class counts
//   mt2  [8][8][36] @ 33792  means k-major, pad-36 (2304)
//   cnt  [8][8]     @ 36096
//   pd   [2048][8]  @ 36160  per-(b,chunk) class dist sums
#define WS_PSUM 0
#define WS_PCNT 32768
#define WS_MT   33792
#define WS_CNT  36096
#define WS_PD   36160

// ---------------------------------------------------------------------------
// Pass 1 (R4-verbatim, nt KEPT — R10 A/B showed removing it costs ~12 µs):
// per-class channel partial sums. One block = (b, c, 16K-px chunk).
// Per-thread LDS slots (stride 9: coprime with 32 banks -> <=2-way, free).
// No atomics. b = f&7: XCD (heuristic f%8) owns one image.
// c==0 blocks also compute label counts (labels L2-hot on re-read).
// ---------------------------------------------------------------------------
__global__ __launch_bounds__(256) void k_pass1(const float* __restrict__ emb,
                                               const int* __restrict__ lab,
                                               float* __restrict__ psum,
                                               float* __restrict__ pcnt) {
    __shared__ float slots[256 * 9];
    __shared__ float red[256];
    const int t = threadIdx.x;
    const int f = blockIdx.x;
    const int b = f & 7;
    const int o = f >> 3;        // 0..511 per image
    const int chunk = o >> 5;    // 0..15
    const int c = o & 31;

    float* myslot = &slots[t * 9];
#pragma unroll
    for (int i = 0; i < 9; ++i) myslot[i] = 0.f;

    const float* e = emb + ((size_t)(b * NC + c)) * HW;
    const int* lb = lab + (size_t)b * HW;
    const int base = chunk * 16384;

    for (int it = 0; it < 16; ++it) {
        const int p = base + it * 1024 + t * 4;
        const int4 l4 = *reinterpret_cast<const int4*>(lb + p);
        const f4 e4 = __builtin_nontemporal_load(reinterpret_cast<const f4*>(e + p));
        myslot[l4.x] += e4.x;
        myslot[l4.y] += e4.y;
        myslot[l4.z] += e4.z;
        myslot[l4.w] += e4.w;
    }
    __syncthreads();

    {   // reduce slots[256][8] -> 8
        const int k = t & 7, r = t >> 3;
        float s = 0.f;
#pragma unroll
        for (int i = 0; i < 8; ++i) s += slots[(r + 32 * i) * 9 + k];
        red[r * 8 + k] = s;
    }
    __syncthreads();
    if (t < 8) {
        float s = 0.f;
#pragma unroll
        for (int r = 0; r < 32; ++r) s += red[r * 8 + t];
        psum[(size_t)f * 8 + t] = s;   // f encodes (b,c,chunk)
    }

    // counts: only c==0 blocks; labels re-read from L2
    if (c == 0) {
        __syncthreads();
#pragma unroll
        for (int i = 0; i < 9; ++i) myslot[i] = 0.f;
        for (int it = 0; it < 16; ++it) {
            const int p = base + it * 1024 + t * 4;
            const int4 l4 = *reinterpret_cast<const int4*>(lb + p);
            myslot[l4.x] += 1.f;
            myslot[l4.y] += 1.f;
            myslot[l4.z] += 1.f;
            myslot[l4.w] += 1.f;
        }
        __syncthreads();
        {
            const int k = t & 7, r = t >> 3;
            float s = 0.f;
#pragma unroll
            for (int i = 0; i < 8; ++i) s += slots[(r + 32 * i) * 9 + k];
            red[r * 8 + k] = s;
        }
        __syncthreads();
        if (t < 8) {
            float s = 0.f;
#pragma unroll
            for (int r = 0; r < 32; ++r) s += red[r * 8 + t];
            pcnt[(b * 16 + chunk) * 8 + t] = s;
        }
    }
}

// ---------------------------------------------------------------------------
// Reduce partials -> means mt2 [b][k][36] (k-major, pad-36) + counts [b][k].
// Same math as R4's k_means; only the output layout changed.
// ---------------------------------------------------------------------------
__global__ __launch_bounds__(256) void k_means(const float* __restrict__ psum,
                                               const float* __restrict__ pcnt,
                                               float* __restrict__ mt2,
                                               float* __restrict__ cnt) {
    const int b = blockIdx.x;
    const int t = threadIdx.x;
    const int c = t >> 3, k = t & 7;

    float cn = 0.f;
#pragma unroll
    for (int ch = 0; ch < 16; ++ch) cn += pcnt[(b * 16 + ch) * 8 + k];

    float s = 0.f;
#pragma unroll
    for (int ch = 0; ch < 16; ++ch) s += psum[(size_t)(b + 8 * (c + 32 * ch)) * 8 + k];

    mt2[b * 288 + k * 36 + c] = s / cn;
    if (c == 0) cnt[b * 8 + k] = cn;
}

// ---------------------------------------------------------------------------
// Pass 2: R4-verbatim EXCEPT the mean lookup. Means in LDS [k][36]
// (k-major, pad-36): per pixel per 4-channel group ONE ds_read_b128
// (bases (l*36+cg)%32 for l=0..7 are 8 disjoint 4-bank spans = all 32
// banks, conflict-free; same-label lanes broadcast). 32 b128 reads per
// thread vs R4's 128 b32 -> 4x fewer LDS instructions.
// One block = (b, 1024-px chunk); 4 px/thread; nt emb loads kept.
// ---------------------------------------------------------------------------
__global__ __launch_bounds__(256) void k_dist(const float* __restrict__ emb,
                                              const int* __restrict__ lab,
                                              const float* __restrict__ mt2,
                                              float* __restrict__ pd) {
    __shared__ float mTs[288];
    __shared__ float slots[256 * 9];
    __shared__ float red[256];
    const int t = threadIdx.x;
    const int f = blockIdx.x;
    const int b = f & 7;
    const int chunk = f >> 3;  // 0..255

    mTs[t] = mt2[b * 288 + t];
    if (t < 32) mTs[256 + t] = mt2[b * 288 + 256 + t];
    float* myslot = &slots[t * 9];
#pragma unroll
    for (int i = 0; i < 9; ++i) myslot[i] = 0.f;
    __syncthreads();

    const int p = chunk * 1024 + t * 4;
    const int4 l4 = *reinterpret_cast<const int4*>(lab + (size_t)b * HW + p);
    const float* e = emb + (size_t)b * NC * HW + p;
    const int m0base = l4.x * 36, m1base = l4.y * 36;
    const int m2base = l4.z * 36, m3base = l4.w * 36;

    float a0 = 0.f, a1 = 0.f, a2 = 0.f, a3 = 0.f;
#pragma unroll
    for (int cg = 0; cg < NC; cg += 4) {
        const f4 m0 = *reinterpret_cast<const f4*>(&mTs[m0base + cg]);
        const f4 m1 = *reinterpret_cast<const f4*>(&mTs[m1base + cg]);
        const f4 m2 = *reinterpret_cast<const f4*>(&mTs[m2base + cg]);
        const f4 m3 = *reinterpret_cast<const f4*>(&mTs[m3base + cg]);
#pragma unroll
        for (int cc = 0; cc < 4; ++cc) {
            const f4 e4 = __builtin_nontemporal_load(
                reinterpret_cast<const f4*>(e + (size_t)(cg + cc) * HW));
            const float d0 = e4.x - m0[cc];
            const float d1 = e4.y - m1[cc];
            const float d2 = e4.z - m2[cc];
            const float d3 = e4.w - m3[cc];
            a0 += d0 * d0;
            a1 += d1 * d1;
            a2 += d2 * d2;
            a3 += d3 * d3;
        }
    }
    myslot[l4.x] += sqrtf(a0);
    myslot[l4.y] += sqrtf(a1);
    myslot[l4.z] += sqrtf(a2);
    myslot[l4.w] += sqrtf(a3);
    __syncthreads();

    {
        const int k = t & 7, r = t >> 3;
        float s = 0.f;
#pragma unroll
        for (int i = 0; i < 8; ++i) s += slots[(r + 32 * i) * 9 + k];
        red[r * 8 + k] = s;
    }
    __syncthreads();
    if (t < 8) {
        float s = 0.f;
#pragma unroll
        for (int r = 0; r < 32; ++r) s += red[r * 8 + t];
        pd[(size_t)f * 8 + t] = s;
    }
}

// ---------------------------------------------------------------------------
// Epilogue (R4-verbatim; hinge reads the [k][36] layout): coalesced pd
// reduce (thread t sums flat idx t, t+256, ...), var + hinge. Deterministic.
// ---------------------------------------------------------------------------
__global__ __launch_bounds__(256) void k_final(const float* __restrict__ pd,
                                               const float* __restrict__ cnt,
                                               const float* __restrict__ mt2,
                                               float* __restrict__ out) {
    __shared__ float partial[256];
    __shared__ float distsum[64];   // [b][k]
    __shared__ float varl[8];
    __shared__ float hingeL[8 * 21];
    const int t = threadIdx.x;

    {
        float s = 0.f;
        for (int j = 0; j < 64; ++j) s += pd[(size_t)j * 256 + t];
        partial[t] = s;
    }
    __syncthreads();
    if (t < 64)
        distsum[t] = partial[t] + partial[t + 64] + partial[t + 128] + partial[t + 192];
    __syncthreads();

    if (t < 8) {
        float v = 0.f;
#pragma unroll
        for (int k = 1; k < 8; ++k)
            v += distsum[t * 8 + k] / cnt[t * 8 + k];
        varl[t] = v;
    }

    if (t < 168) {  // 8 images * 21 pairs among clusters 1..7
        const int b = t / 21;
        const int pr = t - b * 21;
        int ii = 1, jj = 2, c2 = 0;
        for (int a = 1; a <= 7; ++a)
            for (int bb = a + 1; bb <= 7; ++bb) {
                if (c2 == pr) { ii = a; jj = bb; }
                ++c2;
            }
        const float* mTb = mt2 + b * 288;
        float sq = 0.f;
#pragma unroll
        for (int c = 0; c < NC; ++c) {
            const float d = mTb[ii * 36 + c] - mTb[jj * 36 + c];
            sq += d * d;
        }
        const float dist = sqrtf(sq);
        const float gap = 5.0f - dist;  // 2*DD = 5.0
        hingeL[t] = (dist < 5.0f) ? gap * gap : 0.f;
    }
    __syncthreads();
    if (t == 0) {
        float s = 0.f;
#pragma unroll
        for (int b = 0; b < 8; ++b) {
            float h = 0.f;
            for (int pr = 0; pr < 21; ++pr) h += hingeL[b * 21 + pr];
            s += (varl[b] + h * (1.0f / 6.0f)) * (1.0f / 7.0f);
        }
        out[0] = s * 0.125f;
    }
}

extern "C" void kernel_launch(void* const* d_in, const int* in_sizes, int n_in,
                              void* d_out, int out_size, void* d_ws, size_t ws_size,
                              hipStream_t stream) {
    const float* emb = (const float*)d_in[0];
    const int* lab = (const int*)d_in[1];
    float* out = (float*)d_out;
    float* ws = (float*)d_ws;

    float* psum = ws + WS_PSUM;
    float* pcnt = ws + WS_PCNT;
    float* mt2 = ws + WS_MT;
    float* cnt = ws + WS_CNT;
    float* pd = ws + WS_PD;

    k_pass1<<<NB * 16 * NC, 256, 0, stream>>>(emb, lab, psum, pcnt);
    k_means<<<NB, 256, 0, stream>>>(psum, pcnt, mt2, cnt);
    k_dist<<<NB * 256, 256, 0, stream>>>(emb, lab, mt2, pd);
    k_final<<<1, 256, 0, stream>>>(pd, cnt, mt2, out);
}

// Round 13
// 102.922 us; speedup vs baseline: 1.0422x; 1.0134x over previous
//
#include <hip/hip_runtime.h>

// Problem constants (fixed by reference setup_inputs)
#define HW 262144    // 512*512 pixels per image
#define NB 8         // batch
#define NC 32        // channels
#define NK 8         // num classes (NUM_IDS)

typedef float f4 __attribute__((ext_vector_type(4)));

// ws layout (floats) — every slot fully overwritten each launch, no init,
// no atomics anywhere.
//   psum  [4096][8]  @ 0      per-(b,c,chunk) class channel sums
//   pcnt  [128][8]   @ 32768  per-(b,chunk) class counts
//   meansT[8][32][8] @ 33792  transposed [b][c][k]
//   counts[8][8]     @ 35840
//   pdist [2048][8]  @ 35904  per-(b,chunk) class dist sums
#define WS_PSUM 0
#define WS_PCNT 32768
#define WS_MT   33792
#define WS_CNT  35840
#define WS_PD   35904

// ---------------------------------------------------------------------------
// Pass 1 (R4-verbatim, nt kept — R10 showed dropping it costs ~12 µs):
// per-class channel partial sums. One block = (b, c, 16K-px chunk).
// Per-thread LDS slots (stride 9: coprime with 32 banks -> <=2-way, free).
// No atomics. b = f&7: XCD (heuristic f%8) owns one image.
// c==0 blocks also compute label counts (labels L2-hot on re-read).
// ---------------------------------------------------------------------------
__global__ __launch_bounds__(256) void k_pass1(const float* __restrict__ emb,
                                               const int* __restrict__ lab,
                                               float* __restrict__ psum,
                                               float* __restrict__ pcnt) {
    __shared__ float slots[256 * 9];
    __shared__ float red[256];
    const int t = threadIdx.x;
    const int f = blockIdx.x;
    const int b = f & 7;
    const int o = f >> 3;        // 0..511 per image
    const int chunk = o >> 5;    // 0..15
    const int c = o & 31;

    float* myslot = &slots[t * 9];
#pragma unroll
    for (int i = 0; i < 9; ++i) myslot[i] = 0.f;

    const float* e = emb + ((size_t)(b * NC + c)) * HW;
    const int* lb = lab + (size_t)b * HW;
    const int base = chunk * 16384;

    for (int it = 0; it < 16; ++it) {
        const int p = base + it * 1024 + t * 4;
        const int4 l4 = *reinterpret_cast<const int4*>(lb + p);
        const f4 e4 = __builtin_nontemporal_load(reinterpret_cast<const f4*>(e + p));
        myslot[l4.x] += e4.x;
        myslot[l4.y] += e4.y;
        myslot[l4.z] += e4.z;
        myslot[l4.w] += e4.w;
    }
    __syncthreads();

    {   // reduce slots[256][8] -> 8
        const int k = t & 7, r = t >> 3;
        float s = 0.f;
#pragma unroll
        for (int i = 0; i < 8; ++i) s += slots[(r + 32 * i) * 9 + k];
        red[r * 8 + k] = s;
    }
    __syncthreads();
    if (t < 8) {
        float s = 0.f;
#pragma unroll
        for (int r = 0; r < 32; ++r) s += red[r * 8 + t];
        psum[(size_t)f * 8 + t] = s;   // f encodes (b,c,chunk)
    }

    // counts: only c==0 blocks; labels re-read from L2
    if (c == 0) {
        __syncthreads();
#pragma unroll
        for (int i = 0; i < 9; ++i) myslot[i] = 0.f;
        for (int it = 0; it < 16; ++it) {
            const int p = base + it * 1024 + t * 4;
            const int4 l4 = *reinterpret_cast<const int4*>(lb + p);
            myslot[l4.x] += 1.f;
            myslot[l4.y] += 1.f;
            myslot[l4.z] += 1.f;
            myslot[l4.w] += 1.f;
        }
        __syncthreads();
        {
            const int k = t & 7, r = t >> 3;
            float s = 0.f;
#pragma unroll
            for (int i = 0; i < 8; ++i) s += slots[(r + 32 * i) * 9 + k];
            red[r * 8 + k] = s;
        }
        __syncthreads();
        if (t < 8) {
            float s = 0.f;
#pragma unroll
            for (int r = 0; r < 32; ++r) s += red[r * 8 + t];
            pcnt[(b * 16 + chunk) * 8 + t] = s;
        }
    }
}

// ---------------------------------------------------------------------------
// Reduce partials -> meansT [b][c][k] + counts [b][k]. 8 blocks (R4-verbatim).
// ---------------------------------------------------------------------------
__global__ __launch_bounds__(256) void k_means(const float* __restrict__ psum,
                                               const float* __restrict__ pcnt,
                                               float* __restrict__ mt,
                                               float* __restrict__ cnt) {
    const int b = blockIdx.x;
    const int t = threadIdx.x;
    const int c = t >> 3, k = t & 7;

    float cn = 0.f;
#pragma unroll
    for (int ch = 0; ch < 16; ++ch) cn += pcnt[(b * 16 + ch) * 8 + k];

    float s = 0.f;
#pragma unroll
    for (int ch = 0; ch < 16; ++ch) s += psum[(size_t)(b + 8 * (c + 32 * ch)) * 8 + k];

    mt[b * 256 + c * 8 + k] = s / cn;
    if (c == 0) cnt[b * 8 + k] = cn;
}

// ---------------------------------------------------------------------------
// Pass 2: R4-verbatim EXCEPT ONE LINE — the chunk mapping is REVERSED
// (chunk = 255 - (f>>3)). Pass1 finished streaming high pixel indices most
// recently, so the L3 tail is hot there; earliest-dispatched pass2 blocks
// now read that hot tail first instead of the cold head, maximizing
// Infinity-Cache hits before self-eviction (R6: FETCH was 135/264 MB with
// forward order). pd is indexed by (chunk,b) -> same layout as R4's f,
// still bijective under the reversal.
// ---------------------------------------------------------------------------
__global__ __launch_bounds__(256) void k_dist(const float* __restrict__ emb,
                                              const int* __restrict__ lab,
                                              const float* __restrict__ mt,
                                              float* __restrict__ pd) {
    __shared__ float mT[256];
    __shared__ float slots[256 * 9];
    __shared__ float red[256];
    const int t = threadIdx.x;
    const int f = blockIdx.x;
    const int b = f & 7;
    const int chunk = 255 - (f >> 3);  // REVERSED: read L3-hot tail first

    mT[t] = mt[b * 256 + t];
    float* myslot = &slots[t * 9];
#pragma unroll
    for (int i = 0; i < 9; ++i) myslot[i] = 0.f;
    __syncthreads();

    const int p = chunk * 1024 + t * 4;
    const int4 l4 = *reinterpret_cast<const int4*>(lab + (size_t)b * HW + p);
    const float* e = emb + (size_t)b * NC * HW + p;

    float a0 = 0.f, a1 = 0.f, a2 = 0.f, a3 = 0.f;
#pragma unroll 8
    for (int c = 0; c < NC; ++c) {
        const f4 e4 = __builtin_nontemporal_load(reinterpret_cast<const f4*>(e + (size_t)c * HW));
        const float* mrow = &mT[c * 8];
        const float d0 = e4.x - mrow[l4.x];
        const float d1 = e4.y - mrow[l4.y];
        const float d2 = e4.z - mrow[l4.z];
        const float d3 = e4.w - mrow[l4.w];
        a0 += d0 * d0;
        a1 += d1 * d1;
        a2 += d2 * d2;
        a3 += d3 * d3;
    }
    myslot[l4.x] += sqrtf(a0);
    myslot[l4.y] += sqrtf(a1);
    myslot[l4.z] += sqrtf(a2);
    myslot[l4.w] += sqrtf(a3);
    __syncthreads();

    {
        const int k = t & 7, r = t >> 3;
        float s = 0.f;
#pragma unroll
        for (int i = 0; i < 8; ++i) s += slots[(r + 32 * i) * 9 + k];
        red[r * 8 + k] = s;
    }
    __syncthreads();
    if (t < 8) {
        float s = 0.f;
#pragma unroll
        for (int r = 0; r < 32; ++r) s += red[r * 8 + t];
        pd[((size_t)(chunk * 8 + b)) * 8 + t] = s;
    }
}

// ---------------------------------------------------------------------------
// Epilogue (R4-verbatim): coalesced pd reduce (thread t sums flat idx t,
// t+256, ...; residue mod 64 = b*8+k), var + hinge. Deterministic.
// ---------------------------------------------------------------------------
__global__ __launch_bounds__(256) void k_final(const float* __restrict__ pd,
                                               const float* __restrict__ cnt,
                                               const float* __restrict__ mt,
                                               float* __restrict__ out) {
    __shared__ float partial[256];
    __shared__ float distsum[64];   // [b][k]
    __shared__ float varl[8];
    __shared__ float hingeL[8 * 21];
    const int t = threadIdx.x;

    {
        float s = 0.f;
        for (int j = 0; j < 64; ++j) s += pd[(size_t)j * 256 + t];
        partial[t] = s;
    }
    __syncthreads();
    if (t < 64)
        distsum[t] = partial[t] + partial[t + 64] + partial[t + 128] + partial[t + 192];
    __syncthreads();

    if (t < 8) {
        float v = 0.f;
#pragma unroll
        for (int k = 1; k < 8; ++k)
            v += distsum[t * 8 + k] / cnt[t * 8 + k];
        varl[t] = v;
    }

    if (t < 168) {  // 8 images * 21 pairs among clusters 1..7
        const int b = t / 21;
        const int pr = t - b * 21;
        int ii = 1, jj = 2, c2 = 0;
        for (int a = 1; a <= 7; ++a)
            for (int bb = a + 1; bb <= 7; ++bb) {
                if (c2 == pr) { ii = a; jj = bb; }
                ++c2;
            }
        const float* mTb = mt + b * 256;
        float sq = 0.f;
#pragma unroll
        for (int c = 0; c < NC; ++c) {
            const float d = mTb[c * 8 + ii] - mTb[c * 8 + jj];
            sq += d * d;
        }
        const float dist = sqrtf(sq);
        const float gap = 5.0f - dist;  // 2*DD = 5.0
        hingeL[t] = (dist < 5.0f) ? gap * gap : 0.f;
    }
    __syncthreads();
    if (t == 0) {
        float s = 0.f;
#pragma unroll
        for (int b = 0; b < 8; ++b) {
            float h = 0.f;
            for (int pr = 0; pr < 21; ++pr) h += hingeL[b * 21 + pr];
            s += (varl[b] + h * (1.0f / 6.0f)) * (1.0f / 7.0f);
        }
        out[0] = s * 0.125f;
    }
}

extern "C" void kernel_launch(void* const* d_in, const int* in_sizes, int n_in,
                              void* d_out, int out_size, void* d_ws, size_t ws_size,
                              hipStream_t stream) {
    const float* emb = (const float*)d_in[0];
    const int* lab = (const int*)d_in[1];
    float* out = (float*)d_out;
    float* ws = (float*)d_ws;

    float* psum = ws + WS_PSUM;
    float* pcnt = ws + WS_PCNT;
    float* mt = ws + WS_MT;
    float* cnt = ws + WS_CNT;
    float* pd = ws + WS_PD;

    k_pass1<<<NB * 16 * NC, 256, 0, stream>>>(emb, lab, psum, pcnt);
    k_means<<<NB, 256, 0, stream>>>(psum, pcnt, mt, cnt);
    k_dist<<<NB * 256, 256, 0, stream>>>(emb, lab, mt, pd);
    k_final<<<1, 256, 0, stream>>>(pd, cnt, mt, out);
}